// Round 3
// baseline (62.961 us; speedup 1.0000x reference)
//
#include <hip/hip_runtime.h>
#include <cstdint>

#define M_TOT 8192
#define K_PTS 32
#define NCH 64
#define MT 8   // m values per block

typedef float f4 __attribute__((ext_vector_type(4)));

// Single fused kernel.
// Math: score[k][j] (up to j-constant terms that cancel in softmax) =
//   x_k . (A x_j) + u . x_j,  A = (Wq^T Wk)*log2e/8, u = (Wk^T bq)*log2e/8
// Since sum_j attn = 1, output pe[k][c] = relu(Wv[c] . y_k + bv[c]),
//   y_k = sum_j attn[k][j] x_j  (a 3-vector).
__global__ __launch_bounds__(256) void attn_fused(const float* __restrict__ xyz,
                                                  const float* __restrict__ Wq,
                                                  const float* __restrict__ bq,
                                                  const float* __restrict__ Wk,
                                                  const float* __restrict__ Wv,
                                                  const float* __restrict__ bv,
                                                  float* __restrict__ out) {
  // x_lds: [m][j*3+c], row stride 97 -> conflict-free stride-3 reads
  __shared__ __align__(16) float x_lds[MT*97 + 4];
  __shared__ __align__(16) float gh_lds[MT*128]; // [m][j*4 + {g0,g1,g2,h}]
  __shared__ __align__(16) float y_lds[MT*128];  // [m][k*4 + {y0,y1,y2,_}]

  const int t = threadIdx.x;
  const int b = blockIdx.x >> 10;           // grid = 4 * 1024
  const int m0 = (blockIdx.x & 1023) * MT;

  const float* xb = xyz + ((size_t)b * 3 * K_PTS) * M_TOT + m0;

  // ---- issue x loads (3 per thread), latency hidden under the A/u reduction
  float xv[3];
  int rr[3], mm[3];
  #pragma unroll
  for (int p = 0; p < 3; ++p) {
    int i = t + p * 256;
    mm[p] = i & (MT - 1);
    rr[p] = i >> 3;               // r = c*32 + k, 0..95
    xv[p] = xb[(size_t)rr[p] * M_TOT + mm[p]];
  }

  // ---- Wv rows for this thread's phase-2 channels (issue early, L2-hot)
  const int c4 = (t & 15) * 4;
  float w00 = Wv[(c4+0)*3+0], w01 = Wv[(c4+0)*3+1], w02 = Wv[(c4+0)*3+2], bv0 = bv[c4+0];
  float w10 = Wv[(c4+1)*3+0], w11 = Wv[(c4+1)*3+1], w12 = Wv[(c4+1)*3+2], bv1 = bv[c4+1];
  float w20 = Wv[(c4+2)*3+0], w21 = Wv[(c4+2)*3+1], w22 = Wv[(c4+2)*3+2], bv2 = bv[c4+2];
  float w30 = Wv[(c4+3)*3+0], w31 = Wv[(c4+3)*3+1], w32 = Wv[(c4+3)*3+2], bv3 = bv[c4+3];

  // ---- in-block A = Wq^T Wk, u = Wk^T bq via 64-lane butterfly (every wave, redundant)
  const int o = t & 63;
  float wq0 = Wq[o*3+0], wq1 = Wq[o*3+1], wq2 = Wq[o*3+2];
  float wk0 = Wk[o*3+0], wk1 = Wk[o*3+1], wk2 = Wk[o*3+2];
  float bqo = bq[o];
  float A00 = wq0*wk0, A01 = wq0*wk1, A02 = wq0*wk2;
  float A10 = wq1*wk0, A11 = wq1*wk1, A12 = wq1*wk2;
  float A20 = wq2*wk0, A21 = wq2*wk1, A22 = wq2*wk2;
  float u0 = bqo*wk0, u1 = bqo*wk1, u2 = bqo*wk2;
  #pragma unroll
  for (int st = 1; st < 64; st <<= 1) {
    A00 += __shfl_xor(A00, st); A01 += __shfl_xor(A01, st); A02 += __shfl_xor(A02, st);
    A10 += __shfl_xor(A10, st); A11 += __shfl_xor(A11, st); A12 += __shfl_xor(A12, st);
    A20 += __shfl_xor(A20, st); A21 += __shfl_xor(A21, st); A22 += __shfl_xor(A22, st);
    u0  += __shfl_xor(u0,  st); u1  += __shfl_xor(u1,  st); u2  += __shfl_xor(u2,  st);
  }
  const float sc = 1.4426950408889634f / 8.0f; // log2(e)/sqrt(CH)
  A00 *= sc; A01 *= sc; A02 *= sc; A10 *= sc; A11 *= sc; A12 *= sc;
  A20 *= sc; A21 *= sc; A22 *= sc; u0 *= sc; u1 *= sc; u2 *= sc;

  // ---- stash x into LDS
  #pragma unroll
  for (int p = 0; p < 3; ++p) {
    int k = rr[p] & 31, c = rr[p] >> 5;
    x_lds[mm[p]*97 + k*3 + c] = xv[p];
  }
  __syncthreads();

  // ---- Phase 0: per (m,j): g = A x_j, h = u . x_j
  {
    int m = t >> 5, j = t & 31;
    float x0 = x_lds[m*97 + j*3 + 0];
    float x1 = x_lds[m*97 + j*3 + 1];
    float x2 = x_lds[m*97 + j*3 + 2];
    float g0 = fmaf(A02, x2, fmaf(A01, x1, A00 * x0));
    float g1 = fmaf(A12, x2, fmaf(A11, x1, A10 * x0));
    float g2 = fmaf(A22, x2, fmaf(A21, x1, A20 * x0));
    float h  = fmaf(u2,  x2, fmaf(u1,  x1, u0  * x0));
    *(f4*)&gh_lds[m*128 + j*4] = (f4){g0, g1, g2, h};
  }
  __syncthreads();

  // ---- Phase 1: per (m,k): two-pass softmax (no score array -> low VGPR)
  {
    int m = t >> 5, k = t & 31;
    float xk0 = x_lds[m*97 + k*3 + 0];
    float xk1 = x_lds[m*97 + k*3 + 1];
    float xk2 = x_lds[m*97 + k*3 + 2];
    float mx = -3.4e38f;
    #pragma unroll
    for (int j = 0; j < 32; ++j) {
      f4 gh = *(const f4*)&gh_lds[m*128 + j*4];
      float s = fmaf(xk0, gh.x, fmaf(xk1, gh.y, fmaf(xk2, gh.z, gh.w)));
      mx = fmaxf(mx, s);
    }
    float sum = 0.f, y0 = 0.f, y1 = 0.f, y2 = 0.f;
    #pragma unroll
    for (int j = 0; j < 32; ++j) {
      f4 gh = *(const f4*)&gh_lds[m*128 + j*4];
      float s = fmaf(xk0, gh.x, fmaf(xk1, gh.y, fmaf(xk2, gh.z, gh.w)));
      float p = exp2f(s - mx);
      sum += p;
      y0 = fmaf(p, x_lds[m*97 + j*3 + 0], y0);
      y1 = fmaf(p, x_lds[m*97 + j*3 + 1], y1);
      y2 = fmaf(p, x_lds[m*97 + j*3 + 2], y2);
    }
    float inv = 1.0f / sum;
    *(f4*)&y_lds[m*128 + k*4] = (f4){y0*inv, y1*inv, y2*inv, 0.f};
  }
  __syncthreads();

  // ---- Phase 2: per m, two halves; wave's float4 stores cover 1 KB contiguous
  {
    float* op = out + (((size_t)b * M_TOT + m0) * K_PTS) * NCH + c4;
    #pragma unroll
    for (int m = 0; m < MT; ++m) {
      #pragma unroll
      for (int h = 0; h < 2; ++h) {
        int k = (t >> 4) + h * 16;
        f4 y = *(const f4*)&y_lds[m*128 + k*4];
        f4 r;
        r.x = fmaxf(0.f, fmaf(w00, y.x, fmaf(w01, y.y, fmaf(w02, y.z, bv0))));
        r.y = fmaxf(0.f, fmaf(w10, y.x, fmaf(w11, y.y, fmaf(w12, y.z, bv1))));
        r.z = fmaxf(0.f, fmaf(w20, y.x, fmaf(w21, y.y, fmaf(w22, y.z, bv2))));
        r.w = fmaxf(0.f, fmaf(w30, y.x, fmaf(w31, y.y, fmaf(w32, y.z, bv3))));
        __builtin_nontemporal_store(r, (f4*)(op + ((size_t)m * K_PTS + k) * NCH));
      }
    }
  }
}

extern "C" void kernel_launch(void* const* d_in, const int* in_sizes, int n_in,
                              void* d_out, int out_size, void* d_ws, size_t ws_size,
                              hipStream_t stream) {
  const float* xyz = (const float*)d_in[0];
  const float* Wq  = (const float*)d_in[1];
  const float* bq  = (const float*)d_in[2];
  const float* Wk  = (const float*)d_in[3];
  // d_in[4] = bk: cancels in softmax (constant in j), unused
  const float* Wv  = (const float*)d_in[5];
  const float* bv  = (const float*)d_in[6];
  float* out = (float*)d_out;

  attn_fused<<<4096, 256, 0, stream>>>(xyz, Wq, bq, Wk, Wv, bv, out);
}

// Round 4
// 49.499 us; speedup vs baseline: 1.2720x; 1.2720x over previous
//
#include <hip/hip_runtime.h>
#include <cstdint>

#define M_TOT 8192
#define K_PTS 32
#define NCH 64
#define MT 16   // m per block; 4 per wave

typedef float f4 __attribute__((ext_vector_type(4)));

// score[k][j] (up to j-constant terms, which cancel in softmax) =
//   x_k.(A x_j) + u.x_j = (A^T x_k + u) . x_j,  A=(Wq^T Wk)*log2e/8, u=(Wk^T bq)*log2e/8
// sum_j attn = 1  =>  pe[k][c] = relu(Wv[c].y_k + bv[c]),  y_k = sum_j attn[k][j] x_j.
__global__ __launch_bounds__(256) void attn_fused(const float* __restrict__ xyz,
                                                  const float* __restrict__ Wq,
                                                  const float* __restrict__ bq,
                                                  const float* __restrict__ Wk,
                                                  const float* __restrict__ Wv,
                                                  const float* __restrict__ bv,
                                                  float* __restrict__ out) {
  // x4: [m][k] float4 (x0,x1,x2,pad), row stride 132 floats (33 f4) -> staggered banks
  __shared__ __align__(16) float x4[MT * 132 + 4];
  // y: per-wave, per-mpair private region: [w][mp][half][k] float4
  __shared__ __align__(16) float ylds[4 * 512];

  const int t    = threadIdx.x;
  const int w    = t >> 6;
  const int lane = t & 63;
  const int b    = blockIdx.x >> 9;            // grid = 4 * 512
  const int m0   = (blockIdx.x & 511) * MT;

  const float* xb = xyz + ((size_t)b * 3 * K_PTS) * M_TOT + m0;

  // ---- issue staged x loads: 6 per thread, 64B coalesced runs
  float xv[6]; int rr[6], mm[6];
  #pragma unroll
  for (int p = 0; p < 6; ++p) {
    int i = t + p * 256;
    mm[p] = i & 15;
    rr[p] = i >> 4;            // r = c*32 + k, 0..95
    xv[p] = xb[(size_t)rr[p] * M_TOT + mm[p]];
  }

  // ---- Wv rows for this lane's 4 channels (c4*3 floats is 16B aligned: 48B stride)
  const int c4 = (lane & 15) * 4;
  f4 wva = *(const f4*)(Wv + c4 * 3);
  f4 wvb = *(const f4*)(Wv + c4 * 3 + 4);
  f4 wvc = *(const f4*)(Wv + c4 * 3 + 8);
  f4 bvv = *(const f4*)(bv + c4);

  // ---- per-wave butterfly: A = Wq^T Wk, u = Wk^T bq (redundant across waves)
  const int o = lane;
  float wq0 = Wq[o*3+0], wq1 = Wq[o*3+1], wq2 = Wq[o*3+2];
  float wk0 = Wk[o*3+0], wk1 = Wk[o*3+1], wk2 = Wk[o*3+2];
  float bqo = bq[o];
  float A00 = wq0*wk0, A01 = wq0*wk1, A02 = wq0*wk2;
  float A10 = wq1*wk0, A11 = wq1*wk1, A12 = wq1*wk2;
  float A20 = wq2*wk0, A21 = wq2*wk1, A22 = wq2*wk2;
  float u0 = bqo*wk0, u1 = bqo*wk1, u2 = bqo*wk2;
  #pragma unroll
  for (int st = 1; st < 64; st <<= 1) {
    A00 += __shfl_xor(A00, st); A01 += __shfl_xor(A01, st); A02 += __shfl_xor(A02, st);
    A10 += __shfl_xor(A10, st); A11 += __shfl_xor(A11, st); A12 += __shfl_xor(A12, st);
    A20 += __shfl_xor(A20, st); A21 += __shfl_xor(A21, st); A22 += __shfl_xor(A22, st);
    u0  += __shfl_xor(u0,  st); u1  += __shfl_xor(u1,  st); u2  += __shfl_xor(u2,  st);
  }
  const float sc = 1.4426950408889634f / 8.0f; // log2(e)/sqrt(CH)
  A00 *= sc; A01 *= sc; A02 *= sc; A10 *= sc; A11 *= sc; A12 *= sc;
  A20 *= sc; A21 *= sc; A22 *= sc; u0 *= sc; u1 *= sc; u2 *= sc;

  // ---- stash x into LDS (2-way max bank aliasing)
  #pragma unroll
  for (int p = 0; p < 6; ++p) {
    int k = rr[p] & 31, c = rr[p] >> 5;
    x4[mm[p] * 132 + k * 4 + c] = xv[p];
  }
  __syncthreads();   // the ONLY block barrier

  // ---- per wave, fully independent from here: 2 m-pairs
  #pragma unroll
  for (int mp = 0; mp < 2; ++mp) {
    const int half = lane >> 5;
    const int mloc = w * 4 + mp * 2 + half;
    const int k    = lane & 31;

    f4 xk = *(const f4*)&x4[mloc * 132 + k * 4];
    // w_k = A^T x_k + u  (pre-scaled for exp2)
    float wk0r = fmaf(A00, xk.x, fmaf(A10, xk.y, fmaf(A20, xk.z, u0)));
    float wk1r = fmaf(A01, xk.x, fmaf(A11, xk.y, fmaf(A21, xk.z, u1)));
    float wk2r = fmaf(A02, xk.x, fmaf(A12, xk.y, fmaf(A22, xk.z, u2)));

    float sum = 0.f, y0 = 0.f, y1 = 0.f, y2 = 0.f;
    #pragma unroll
    for (int j = 0; j < 32; ++j) {
      f4 xj = *(const f4*)&x4[mloc * 132 + j * 4];   // broadcast per half-wave
      float s = fmaf(wk0r, xj.x, fmaf(wk1r, xj.y, wk2r * xj.z));
      float p = exp2f(s);                             // no max-sub: |s| <~ 40, safe in fp32
      sum += p;
      y0 = fmaf(p, xj.x, y0);
      y1 = fmaf(p, xj.y, y1);
      y2 = fmaf(p, xj.z, y2);
    }
    float inv = 1.0f / sum;

    float* yw = &ylds[w * 512 + mp * 256];
    *(f4*)&yw[(half * 32 + k) * 4] = (f4){y0 * inv, y1 * inv, y2 * inv, 0.f};
    // within-wave LDS RAW: drain DS queue (in-order per wave), keep compiler honest
    __asm__ volatile("s_waitcnt lgkmcnt(0)" ::: "memory");

    // ---- store this m-pair: 16 iterations x 1KB contiguous per wave-instr
    float* op = out + (((size_t)b * M_TOT + m0 + w * 4 + mp * 2) * K_PTS) * NCH;
    #pragma unroll
    for (int it = 0; it < 16; ++it) {
      int msel = it >> 3;
      int kk   = (it & 7) * 4 + (lane >> 4);
      f4 y = *(const f4*)&yw[(msel * 32 + kk) * 4];
      f4 r;
      r.x = fmaxf(0.f, fmaf(wva.x, y.x, fmaf(wva.y, y.y, fmaf(wva.z, y.z, bvv.x))));
      r.y = fmaxf(0.f, fmaf(wva.w, y.x, fmaf(wvb.x, y.y, fmaf(wvb.y, y.z, bvv.y))));
      r.z = fmaxf(0.f, fmaf(wvb.z, y.x, fmaf(wvb.w, y.y, fmaf(wvc.x, y.z, bvv.z))));
      r.w = fmaxf(0.f, fmaf(wvc.y, y.x, fmaf(wvc.z, y.y, fmaf(wvc.w, y.z, bvv.w))));
      *(f4*)(op + ((size_t)(msel * K_PTS + kk)) * NCH + c4) = r;
    }
  }
}

extern "C" void kernel_launch(void* const* d_in, const int* in_sizes, int n_in,
                              void* d_out, int out_size, void* d_ws, size_t ws_size,
                              hipStream_t stream) {
  const float* xyz = (const float*)d_in[0];
  const float* Wq  = (const float*)d_in[1];
  const float* bq  = (const float*)d_in[2];
  const float* Wk  = (const float*)d_in[3];
  // d_in[4] = bk: constant in j, cancels in softmax — unused
  const float* Wv  = (const float*)d_in[5];
  const float* bv  = (const float*)d_in[6];
  float* out = (float*)d_out;

  attn_fused<<<2048, 256, 0, stream>>>(xyz, Wq, bq, Wk, Wv, bv, out);
}